// Round 4
// baseline (1355.657 us; speedup 1.0000x reference)
//
#include <hip/hip_runtime.h>
#include <math.h>

// Problem constants (B,T,D) = (16,1024,1024)
#define BB 16
#define TT 1024
#define DD 1024
#define M_TOT (BB * TT)   // 16384 GEMM rows

typedef double v4d __attribute__((ext_vector_type(4)));
typedef double v2d __attribute__((ext_vector_type(2)));

#define CNOISE (0.005 * 0.15)   // NOISE_SCALE * THRESHOLD

// ---------------- Kernel 1: xt = tanh(0.5 * x) in double ----------------
// fp64 needed: GEMM-input error ~1e-10 keeps accumulated ic error ~1e-9 so
// expected spike flips << 1 over 16.7M threshold comparisons.
__global__ void k_tanh_xt(const float* __restrict__ x, double* __restrict__ xt) {
    const size_t i = ((size_t)blockIdx.x * blockDim.x + threadIdx.x) * 4;
    const float4 v = *(const float4*)(x + i);
    xt[i + 0] = tanh((double)v.x * 0.5);
    xt[i + 1] = tanh((double)v.y * 0.5);
    xt[i + 2] = tanh((double)v.z * 0.5);
    xt[i + 3] = tanh((double)v.w * 0.5);
}

// ---------------- Kernel 2: fp64 MFMA GEMM, dbuf LDS, 64x64 wave tile ----------------
// icq[(t*BB+b)*DD+e] = tanh(xt @ W^T) + noise*CNOISE + 1e-6  (fp64, t-major)
// C/D layout of v_mfma_f64_16x16x4f64 probed at runtime (R2 lesson):
// D1=mfma(rowcode,1,0)=4*row, D2=mfma(1,rowcode,0)=4*col per slot.
#define BM 128
#define BN 128
#define BK 16
#define RS 18   // row stride (doubles): even -> 16B-aligned rows; 4-lane/bank-pair balanced reads (0 conflicts in R3)

__launch_bounds__(256, 2)
__global__ void k_gemm_tanh_mfma(const double* __restrict__ A, const float* __restrict__ W,
                                 const float* __restrict__ noise, double* __restrict__ icq) {
    __shared__ double As[2][BM][RS];  // [buf][m][k]
    __shared__ double Bs[2][BN][RS];  // [buf][e][k]

    const int tid = threadIdx.x;
    const int l  = tid & 63;
    const int w  = tid >> 6;          // wave 0..3
    const int wm = (w & 1) * 64;      // wave m offset
    const int wn = (w >> 1) * 64;     // wave e offset
    const int lr = l & 15;            // M/N index within 16
    const int lg = l >> 4;            // K group 0..3

    const int m0 = (blockIdx.x >> 3) * BM;   // 128 m-blocks
    const int e0 = (blockIdx.x & 7) * BN;    // 8 e-blocks

    // ---- Runtime C/D layout probe (2 MFMAs, negligible) ----
    v4d zc = {};
    const double rowcode = (double)lr;
    v4d d1 = __builtin_amdgcn_mfma_f64_16x16x4f64(rowcode, 1.0, zc, 0, 0, 0);  // 4*row
    v4d d2 = __builtin_amdgcn_mfma_f64_16x16x4f64(1.0, rowcode, zc, 0, 0, 0);  // 4*col
    int am[4], bn[4];
#pragma unroll
    for (int ei = 0; ei < 4; ++ei) {
        am[ei] = ((int)d1[ei]) >> 2;
        bn[ei] = ((int)d2[ei]) >> 2;
    }

    // staging indices: thread covers rows sm+32i, col pair sc (2 doubles)
    const int sm = tid >> 3;        // 0..31
    const int sc = (tid & 7) * 2;   // 0,2,..,14

    v4d acc[4][4] = {};  // [mt][nt], 64x64 per wave

    // ---- Prologue: stage chunk 0 into buf 0 ----
#pragma unroll
    for (int i = 0; i < 4; ++i) {
        const int mrow = sm + 32 * i;
        v2d a2 = *(const v2d*)&A[(size_t)(m0 + mrow) * DD + sc];
        *(v2d*)&As[0][mrow][sc] = a2;
        const float2 f = *(const float2*)&W[(size_t)(e0 + mrow) * DD + sc];
        v2d b2; b2[0] = (double)f.x; b2[1] = (double)f.y;
        *(v2d*)&Bs[0][mrow][sc] = b2;
    }
    __syncthreads();

    for (int kt = 0; kt < DD; kt += BK) {
        const int cur = (kt >> 4) & 1;
        const int nxt = cur ^ 1;
        const bool more = (kt + BK) < DD;

        // Issue next-chunk global loads BEFORE compute (latency hides under 4096 MFMA cyc)
        v2d pa[4]; float2 pb[4];
        if (more) {
#pragma unroll
            for (int i = 0; i < 4; ++i) {
                const int mrow = sm + 32 * i;
                pa[i] = *(const v2d*)&A[(size_t)(m0 + mrow) * DD + kt + BK + sc];
                pb[i] = *(const float2*)&W[(size_t)(e0 + mrow) * DD + kt + BK + sc];
            }
        }

        // Compute: 4 s-iters x 16 MFMA
#pragma unroll
        for (int s = 0; s < 4; ++s) {
            const int kk = 4 * s + lg;
            double a[4], b[4];
#pragma unroll
            for (int mt = 0; mt < 4; ++mt) a[mt] = As[cur][wm + 16 * mt + lr][kk];
#pragma unroll
            for (int nt = 0; nt < 4; ++nt) b[nt] = Bs[cur][wn + 16 * nt + lr][kk];
#pragma unroll
            for (int mt = 0; mt < 4; ++mt)
#pragma unroll
                for (int nt = 0; nt < 4; ++nt)
                    acc[mt][nt] = __builtin_amdgcn_mfma_f64_16x16x4f64(a[mt], b[nt], acc[mt][nt], 0, 0, 0);
        }

        // Write prefetched chunk into the other buffer
        if (more) {
#pragma unroll
            for (int i = 0; i < 4; ++i) {
                const int mrow = sm + 32 * i;
                *(v2d*)&As[nxt][mrow][sc] = pa[i];
                v2d b2; b2[0] = (double)pb[i].x; b2[1] = (double)pb[i].y;
                *(v2d*)&Bs[nxt][mrow][sc] = b2;
            }
        }
        __syncthreads();  // one barrier per chunk (prev-iter barrier protects nxt's old readers)
    }

    // ---- Epilogue: icq = tanh(acc) + noise*c + 1e-6 (fp64), scatter t-major ----
#pragma unroll
    for (int mt = 0; mt < 4; ++mt) {
#pragma unroll
        for (int ei = 0; ei < 4; ++ei) {
            const int m = m0 + wm + 16 * mt + am[ei];
            const int b = m >> 10;       // m = b*TT + t
            const int t = m & 1023;
            const size_t rowbase = (size_t)(t * BB + b) * DD;
#pragma unroll
            for (int nt = 0; nt < 4; ++nt) {
                const int e = e0 + wn + 16 * nt + bn[ei];
                const double nq = (double)noise[(size_t)m * DD + e] * CNOISE + 1e-6;
                icq[rowbase + e] = tanh(acc[mt][nt][ei]) + nq;
            }
        }
    }
}

// ---------------- Kernel 3: LIF scan + fused output epilogue ----------------
// Serial chain is now a single fp64 fma per step: mem = fma(0.95, mem, icq).
// ic for the output path reconstructed in f32 (err 6e-8 << 6.4e-3 threshold).
#define CH 16

__device__ __forceinline__ float fast_tanhf(float v) {
    const float e = __expf(2.0f * v);
    return 1.0f - 2.0f / (e + 1.0f);
}

__global__ void k_scan(const double* __restrict__ icq, const float* __restrict__ noise,
                       const float* __restrict__ x, const float* __restrict__ res_scale,
                       float* __restrict__ out) {
    const int tid = blockIdx.x * blockDim.x + threadIdx.x;  // 0..16383
    const int b = tid >> 10;
    const int e = tid & 1023;

    const double r = 1.0 / (1.0 + exp(-(double)res_scale[0]));
    const float rf = (float)r;
    const float omrf = (float)(1.0 - r);

    const size_t bte = (size_t)b * (TT * DD) + e;  // base for [b, t=0, e]

    double qc[CH], qn[CH];
    float nc[CH], nn[CH], xc[CH], xn[CH];

#pragma unroll
    for (int i = 0; i < CH; ++i) {
        qc[i] = icq[(size_t)(i * BB + b) * DD + e];
        nc[i] = noise[bte + (size_t)i * DD];
        xc[i] = x[bte + (size_t)i * DD];
    }

    double mem = 0.0;
    for (int t0 = 0; t0 < TT; t0 += CH) {
        const bool has_next = (t0 + CH) < TT;
        if (has_next) {
            const int tn = t0 + CH;
#pragma unroll
            for (int i = 0; i < CH; ++i) {
                qn[i] = icq[(size_t)((tn + i) * BB + b) * DD + e];
                nn[i] = noise[bte + (size_t)(tn + i) * DD];
                xn[i] = x[bte + (size_t)(tn + i) * DD];
            }
        }
#pragma unroll
        for (int i = 0; i < CH; ++i) {
            const int t = t0 + i;
            const double q = qc[i];
            mem = fma(0.95, mem, q);            // chain: fma -> cmp -> select
            const bool s = (mem >= 0.15);
            const float icf = (float)(q - ((double)nc[i] * CNOISE + 1e-6));
            const float raw = s ? icf * 0.5f : 0.0f;
            const float xt = fast_tanhf(0.5f * xc[i]);
            out[bte + (size_t)t * DD] = fast_tanhf((rf * raw + omrf * xt) * 0.5f);
            mem = s ? -0.05 : mem;
        }
        if (has_next) {
#pragma unroll
            for (int i = 0; i < CH; ++i) { qc[i] = qn[i]; nc[i] = nn[i]; xc[i] = xn[i]; }
        }
    }
}

// ---------------- Launch ----------------
extern "C" void kernel_launch(void* const* d_in, const int* in_sizes, int n_in,
                              void* d_out, int out_size, void* d_ws, size_t ws_size,
                              hipStream_t stream) {
    const float* x     = (const float*)d_in[0];   // (B,T,D) f32
    const float* W     = (const float*)d_in[1];   // (D,D) f32
    const float* rs    = (const float*)d_in[2];   // scalar f32
    const float* noise = (const float*)d_in[3];   // (B,T,D) f32
    float* out = (float*)d_out;

    // ws layout: xt (double, 16M) | icq (double, 16M)  => 256 MB total
    double* xt  = (double*)d_ws;
    double* icq = xt + (size_t)M_TOT * DD;

    k_tanh_xt<<<(M_TOT * DD) / (256 * 4), 256, 0, stream>>>(x, xt);

    k_gemm_tanh_mfma<<<(M_TOT / BM) * (DD / BN), 256, 0, stream>>>(xt, W, noise, icq);

    k_scan<<<M_TOT / 64, 64, 0, stream>>>(icq, noise, x, rs, out);
}

// Round 5
// 930.685 us; speedup vs baseline: 1.4566x; 1.4566x over previous
//
#include <hip/hip_runtime.h>
#include <math.h>

// Problem constants (B,T,D) = (16,1024,1024)
#define BB 16
#define TT 1024
#define DD 1024
#define M_TOT (BB * TT)   // 16384 GEMM rows / LIF chains

typedef double v4d __attribute__((ext_vector_type(4)));
typedef double v2d __attribute__((ext_vector_type(2)));

#define CNOISE (0.005 * 0.15)   // NOISE_SCALE * THRESHOLD

// ---------------- Kernel 1: xt = tanh(0.5 * x) in double ----------------
// fp64 needed: GEMM-input error ~1e-10 keeps accumulated ic error ~1e-9 so
// expected spike flips << 1 over 16.7M threshold comparisons.
__global__ void k_tanh_xt(const float* __restrict__ x, double* __restrict__ xt) {
    const size_t i = ((size_t)blockIdx.x * blockDim.x + threadIdx.x) * 4;
    const float4 v = *(const float4*)(x + i);
    xt[i + 0] = tanh((double)v.x * 0.5);
    xt[i + 1] = tanh((double)v.y * 0.5);
    xt[i + 2] = tanh((double)v.z * 0.5);
    xt[i + 3] = tanh((double)v.w * 0.5);
}

// ---------------- Kernel 2: fp64 MFMA GEMM, dbuf LDS, 64x64 wave tile ----------------
// icq[t*16384 + b*1024 + e] = tanh(xt @ W^T) + noise*CNOISE + 1e-6  (fp64, t-major)
// C/D layout of v_mfma_f64_16x16x4f64 probed at runtime (R2 lesson).
// RS=17 (odd): frag-read bank = (2*lr + 2k) mod 32 -> conflict-free (R3 measured 0;
// R4's RS=18 measured 3.4e7 conflict-cycles and capped MfmaUtil at 70%).
#define BM 128
#define BN 128
#define BK 16
#define RS 17

__launch_bounds__(256, 2)
__global__ void k_gemm_tanh_mfma(const double* __restrict__ A, const float* __restrict__ W,
                                 const float* __restrict__ noise, double* __restrict__ icq) {
    __shared__ double As[2][BM][RS];  // [buf][m][k]
    __shared__ double Bs[2][BN][RS];  // [buf][e][k]

    const int tid = threadIdx.x;
    const int l  = tid & 63;
    const int w  = tid >> 6;          // wave 0..3
    const int wm = (w & 1) * 64;      // wave m offset
    const int wn = (w >> 1) * 64;     // wave e offset
    const int lr = l & 15;            // M/N index within 16
    const int lg = l >> 4;            // K group 0..3

    const int m0 = (blockIdx.x >> 3) * BM;   // 128 m-blocks
    const int e0 = (blockIdx.x & 7) * BN;    // 8 e-blocks

    // ---- Runtime C/D layout probe (2 MFMAs, negligible) ----
    v4d zc = {};
    const double rowcode = (double)lr;
    v4d d1 = __builtin_amdgcn_mfma_f64_16x16x4f64(rowcode, 1.0, zc, 0, 0, 0);  // 4*row
    v4d d2 = __builtin_amdgcn_mfma_f64_16x16x4f64(1.0, rowcode, zc, 0, 0, 0);  // 4*col
    int am[4], bn[4];
#pragma unroll
    for (int ei = 0; ei < 4; ++ei) {
        am[ei] = ((int)d1[ei]) >> 2;
        bn[ei] = ((int)d2[ei]) >> 2;
    }

    // staging indices: thread covers rows sm+32i, col pair sc..sc+1
    const int sm = tid >> 3;        // 0..31
    const int sc = (tid & 7) * 2;   // 0,2,..,14

    v4d acc[4][4] = {};  // [mt][nt], 64x64 per wave

    // ---- Prologue: stage chunk 0 into buf 0 (scalar LDS stores: odd-stride rows) ----
#pragma unroll
    for (int i = 0; i < 4; ++i) {
        const int mrow = sm + 32 * i;
        v2d a2 = *(const v2d*)&A[(size_t)(m0 + mrow) * DD + sc];
        As[0][mrow][sc]     = a2[0];
        As[0][mrow][sc + 1] = a2[1];
        const float2 f = *(const float2*)&W[(size_t)(e0 + mrow) * DD + sc];
        Bs[0][mrow][sc]     = (double)f.x;
        Bs[0][mrow][sc + 1] = (double)f.y;
    }
    __syncthreads();

    for (int kt = 0; kt < DD; kt += BK) {
        const int cur = (kt >> 4) & 1;
        const int nxt = cur ^ 1;
        const bool more = (kt + BK) < DD;

        // Issue next-chunk global loads BEFORE compute (latency hides under 4096 MFMA cyc)
        v2d pa[4]; float2 pb[4];
        if (more) {
#pragma unroll
            for (int i = 0; i < 4; ++i) {
                const int mrow = sm + 32 * i;
                pa[i] = *(const v2d*)&A[(size_t)(m0 + mrow) * DD + kt + BK + sc];
                pb[i] = *(const float2*)&W[(size_t)(e0 + mrow) * DD + kt + BK + sc];
            }
        }

        // Compute: 4 s-iters x 16 MFMA = 64 MFMA (4096 cyc) per chunk
#pragma unroll
        for (int s = 0; s < 4; ++s) {
            const int kk = 4 * s + lg;
            double a[4], b[4];
#pragma unroll
            for (int mt = 0; mt < 4; ++mt) a[mt] = As[cur][wm + 16 * mt + lr][kk];
#pragma unroll
            for (int nt = 0; nt < 4; ++nt) b[nt] = Bs[cur][wn + 16 * nt + lr][kk];
#pragma unroll
            for (int mt = 0; mt < 4; ++mt)
#pragma unroll
                for (int nt = 0; nt < 4; ++nt)
                    acc[mt][nt] = __builtin_amdgcn_mfma_f64_16x16x4f64(a[mt], b[nt], acc[mt][nt], 0, 0, 0);
        }

        // Write prefetched chunk into the other buffer
        if (more) {
#pragma unroll
            for (int i = 0; i < 4; ++i) {
                const int mrow = sm + 32 * i;
                As[nxt][mrow][sc]     = pa[i][0];
                As[nxt][mrow][sc + 1] = pa[i][1];
                Bs[nxt][mrow][sc]     = (double)pb[i].x;
                Bs[nxt][mrow][sc + 1] = (double)pb[i].y;
            }
        }
        __syncthreads();
    }

    // ---- Epilogue: icq = tanh(acc) + noise*c + 1e-6 (fp64), scatter t-major ----
#pragma unroll
    for (int mt = 0; mt < 4; ++mt) {
#pragma unroll
        for (int ei = 0; ei < 4; ++ei) {
            const int m = m0 + wm + 16 * mt + am[ei];
            const int b = m >> 10;       // m = b*TT + t
            const int t = m & 1023;
            const size_t rowbase = (size_t)(t * BB + b) * DD;
#pragma unroll
            for (int nt = 0; nt < 4; ++nt) {
                const int e = e0 + wn + 16 * nt + bn[ei];
                const double nq = (double)noise[(size_t)m * DD + e] * CNOISE + 1e-6;
                icq[rowbase + e] = tanh(acc[mt][nt][ei]) + nq;
            }
        }
    }
}

// ---------------- Kernel 3a: serial LIF chain -> spike bytes ----------------
// Single coalesced stream: icq[t*16384 + tid]. CH=16 deep prefetch (only 32 VGPRs
// of state now) => ~8KB in flight/wave, 256 waves => ~2MB in flight ~ 5 TB/s.
#define SCH 16

__global__ void k_scan_spikes(const double* __restrict__ icq, unsigned char* __restrict__ spk) {
    const int tid = blockIdx.x * blockDim.x + threadIdx.x;  // chain id = b*1024+e
    const double* p = icq + tid;
    unsigned char* q = spk + tid;

    double qc[SCH], qn[SCH];
#pragma unroll
    for (int i = 0; i < SCH; ++i) qc[i] = p[(size_t)i * M_TOT];

    double mem = 0.0;
    for (int t0 = 0; t0 < TT; t0 += SCH) {
        const bool has_next = (t0 + SCH) < TT;
        if (has_next) {
#pragma unroll
            for (int i = 0; i < SCH; ++i) qn[i] = p[(size_t)(t0 + SCH + i) * M_TOT];
        }
#pragma unroll
        for (int i = 0; i < SCH; ++i) {
            mem = fma(0.95, mem, qc[i]);        // icq already folds noise*c + 1e-6
            const bool s = (mem >= 0.15);
            q[(size_t)(t0 + i) * M_TOT] = s ? 1 : 0;
            mem = s ? -0.05 : mem;
        }
        if (has_next) {
#pragma unroll
            for (int i = 0; i < SCH; ++i) qc[i] = qn[i];
        }
    }
}

// ---------------- Kernel 3b: elementwise output epilogue (full occupancy) ----------------
// out = tanh((r*(s*ic*0.5) + (1-r)*tanh(0.5x)) * 0.5), all f32 (err ~1e-7 << 6.4e-3).
__device__ __forceinline__ float fast_tanhf(float v) {
    const float e = __expf(2.0f * v);
    return 1.0f - 2.0f / (e + 1.0f);
}

__global__ void k_epilogue(const double* __restrict__ icq, const float* __restrict__ noise,
                           const float* __restrict__ x, const unsigned char* __restrict__ spk,
                           const float* __restrict__ res_scale, float* __restrict__ out) {
    const size_t i = ((size_t)blockIdx.x * blockDim.x + threadIdx.x) * 4;  // (b,t,e) flat
    const int b = (int)(i >> 20);
    const int t = (int)(i >> 10) & 1023;
    const int e = (int)i & 1023;
    const size_t j = (((size_t)t * BB + b) << 10) + e;  // t-major flat

    const float rf = 1.0f / (1.0f + __expf(-res_scale[0]));
    const float omrf = 1.0f - rf;

    const float4 nz = *(const float4*)(noise + i);
    const float4 xv = *(const float4*)(x + i);
    const v2d q01 = *(const v2d*)(icq + j);
    const v2d q23 = *(const v2d*)(icq + j + 2);
    const uchar4 sv = *(const uchar4*)(spk + j);

    float qf[4] = {(float)q01[0], (float)q01[1], (float)q23[0], (float)q23[1]};
    float nf[4] = {nz.x, nz.y, nz.z, nz.w};
    float xf[4] = {xv.x, xv.y, xv.z, xv.w};
    unsigned char sf[4] = {sv.x, sv.y, sv.z, sv.w};

    float4 o;
    float* op = &o.x;
#pragma unroll
    for (int u = 0; u < 4; ++u) {
        const float icf = qf[u] - fmaf(nf[u], (float)CNOISE, 1e-6f);  // undo folded noise
        const float raw = sf[u] ? icf * 0.5f : 0.0f;
        const float xtt = fast_tanhf(0.5f * xf[u]);
        op[u] = fast_tanhf((rf * raw + omrf * xtt) * 0.5f);
    }
    *(float4*)(out + i) = o;
}

// ---------------- Launch ----------------
extern "C" void kernel_launch(void* const* d_in, const int* in_sizes, int n_in,
                              void* d_out, int out_size, void* d_ws, size_t ws_size,
                              hipStream_t stream) {
    const float* x     = (const float*)d_in[0];   // (B,T,D) f32
    const float* W     = (const float*)d_in[1];   // (D,D) f32
    const float* rs    = (const float*)d_in[2];   // scalar f32
    const float* noise = (const float*)d_in[3];   // (B,T,D) f32
    float* out = (float*)d_out;

    // ws layout: xt (double, 16M) | icq (double, 16M) => 256 MB.
    // After the GEMM, xt is dead — its region is reused for the spike bytes (16.7 MB).
    double* xt  = (double*)d_ws;
    double* icq = xt + (size_t)M_TOT * DD;
    unsigned char* spk = (unsigned char*)d_ws;

    k_tanh_xt<<<(M_TOT * DD) / (256 * 4), 256, 0, stream>>>(x, xt);

    k_gemm_tanh_mfma<<<(M_TOT / BM) * (DD / BN), 256, 0, stream>>>(xt, W, noise, icq);

    k_scan_spikes<<<M_TOT / 256, 256, 0, stream>>>(icq, spk);

    k_epilogue<<<(M_TOT * DD) / (256 * 4), 256, 0, stream>>>(icq, noise, x, spk, rs, out);
}